// Round 7
// baseline (42.577 us; speedup 1.0000x reference)
//
#include <hip/hip_runtime.h>
#include <math.h>

#define HH 256
#define WW 256
#define BB 32
#define NW 8  // 256 rows = 8 x u32 words per column bitmask

// ---------------------------------------------------------------------------
// Kernel A: build column bitmasks.  P bit = (pred > 0.5), T bit = (target==1).
// Grid: BB*NW*4 = 1024 blocks; block = (b, word-row j, column-quarter wq).
// ---------------------------------------------------------------------------
__global__ __launch_bounds__(256) void bitmask_kernel(
    const float* __restrict__ pred, const float* __restrict__ tgt,
    unsigned int* __restrict__ P, unsigned int* __restrict__ T) {
  const int b  = blockIdx.x >> 5;
  const int j  = (blockIdx.x >> 2) & 7;
  const int wq = blockIdx.x & 3;
  const int r    = threadIdx.x >> 6;   // wave id: row-subset (8 rows)
  const int lane = threadIdx.x & 63;
  const int col  = wq * 64 + lane;
  const int row0 = j * 32 + r * 8;

  const float* pin = pred + (size_t)b * (HH * WW) + row0 * WW + col;
  const float* tin = tgt  + (size_t)b * (HH * WW) + row0 * WW + col;
  unsigned int pb = 0, tb = 0;
#pragma unroll
  for (int i = 0; i < 8; ++i) {
    pb |= (pin[i * WW] > 0.5f ? 1u : 0u) << i;
    tb |= (tin[i * WW] == 1.0f ? 1u : 0u) << i;
  }

  __shared__ unsigned int sP[4][64], sT[4][64];
  sP[r][lane] = pb << (r * 8);
  sT[r][lane] = tb << (r * 8);
  __syncthreads();
  if (r == 0) {
    P[((size_t)b * NW + j) * WW + col] =
        sP[0][lane] | sP[1][lane] | sP[2][lane] | sP[3][lane];
    T[((size_t)b * NW + j) * WW + col] =
        sT[0][lane] | sT[1][lane] | sT[2][lane] | sT[3][lane];
  }
}

// ---------------------------------------------------------------------------
// Kernel A2: per-column 1D distance to nearest DIFFERING pixel via edge
// masks; writes SIGN-ENCODED squared distance:  own-bit ? -g^2 : +g^2.
// Grid: BB*16 blocks; block = (b, map*8+j); thread = column w.
// ---------------------------------------------------------------------------
__global__ __launch_bounds__(256) void coledt_kernel(
    const unsigned int* __restrict__ P, const unsigned int* __restrict__ T,
    float* __restrict__ DP2, float* __restrict__ DT2) {
  const int b  = blockIdx.x >> 4;
  const int mj = blockIdx.x & 15;
  const int mp = mj >> 3;        // 0: pred mask, 1: target mask
  const int j  = mj & 7;         // 32-row word this thread produces
  const int w  = threadIdx.x;

  const unsigned int* M = mp ? T : P;
  float* OUT = mp ? DT2 : DP2;

  unsigned int Wd[NW];
#pragma unroll
  for (int jj = 0; jj < NW; ++jj)
    Wd[jj] = M[((size_t)b * NW + jj) * WW + w];

  // edge words: bit p of E[jj] = (bit p != bit p+1)
  unsigned int E[NW];
#pragma unroll
  for (int jj = 0; jj < NW - 1; ++jj)
    E[jj] = Wd[jj] ^ ((Wd[jj] >> 1) | (Wd[jj + 1] << 31));
  E[NW - 1] = (Wd[NW - 1] ^ (Wd[NW - 1] >> 1)) & 0x7FFFFFFFu;  // no edge at 255

  // select this block's words (j uniform; static indices only)
  unsigned int EJ = 0, EJm1 = 0, WJ = 0;
#pragma unroll
  for (int jj = 0; jj < NW; ++jj) {
    if (j == jj) { EJ = E[jj]; WJ = Wd[jj]; }
    if (j - 1 == jj) EJm1 = E[jj];
  }

  // down-carry: highest edge position <= base-1 among words below
  int emax = -100000;
#pragma unroll
  for (int jj = 0; jj < NW - 1; ++jj)
    if (jj < j && E[jj]) emax = 32 * jj + 31 - __builtin_clz(E[jj]);
  int D = (j * 32 - 1) - emax;
  if (D > 513) D = 513;

  // up-carry: lowest edge position >= base+32 among words above
  int emin = 100000;
#pragma unroll
  for (int jj = NW - 1; jj >= 1; --jj)
    if (jj > j && E[jj]) emin = 32 * jj + __builtin_ctz(E[jj]);
  int U = (emin + 1) - (j * 32 + 32);
  if (U > 513) U = 513;

  // query-aligned edge word for the down chain: bit i = edge at (base+i-1)
  const unsigned int EQ = (EJ << 1) | (j ? (EJm1 >> 31) : 0u);

  // down chain (ascending), pack u16 pairs
  unsigned int dn[16];
#pragma unroll
  for (int i = 0; i < 32; ++i) {
    D = ((EQ >> i) & 1u) ? 1 : (D + 1);
    if (i & 1) dn[i >> 1] |= (unsigned int)D << 16;
    else       dn[i >> 1] = (unsigned int)D;
  }

  // up chain (descending) + combine + sign-encode + coalesced store
  const size_t obase = (size_t)b * (HH * WW) + (size_t)(j * 32) * WW + w;
#pragma unroll
  for (int i = 31; i >= 0; --i) {
    U = ((EJ >> i) & 1u) ? 1 : (U + 1);
    int dnv = (int)((dn[i >> 1] >> ((i & 1) * 16)) & 0xFFFFu);
    int g = min(min(dnv, U), 512);       // cap = H+W (exact, incl. empty cols)
    float g2 = (float)(g * g);
    OUT[obase + (size_t)i * WW] = ((WJ >> i) & 1u) ? -g2 : g2;
  }
}

// ---------------------------------------------------------------------------
// Kernel B: WAVE-PER-ROW min-plus, 4-step-grouped k-loop with a single
// uniform __all break per group (attacks per-iteration dependent-branch
// latency; extra fmins past the exact exit point are no-ops -> still exact).
// Lane owns 4 CONSECUTIVE columns -> float4 global loads.  No barriers.
// ---------------------------------------------------------------------------
__global__ __launch_bounds__(256) void minplus_kernel(
    const float* __restrict__ DP2, const float* __restrict__ DT2,
    float* __restrict__ partial) {
  const int wv = threadIdx.x >> 6;
  const int lane = threadIdx.x & 63;
  const int row = blockIdx.x * 4 + wv;   // b*HH + h
  const size_t rbase = (size_t)row * WW;
  const int y0 = 4 * lane;

  __shared__ float4 s[4][WW];

  const float4 vp = *(const float4*)(DP2 + rbase + y0);
  const float4 vt = *(const float4*)(DT2 + rbase + y0);

  float m[4][4];  // [col-offset][map], all indices static after unroll
#define DEMUX(c, pc, tc)                                               \
  {                                                                    \
    float4 v = make_float4(fmaxf(pc, 0.f), fmaxf(-(pc), 0.f),          \
                           fmaxf(tc, 0.f), fmaxf(-(tc), 0.f));         \
    s[wv][y0 + c] = v;                                                 \
    m[c][0] = v.x; m[c][1] = v.y; m[c][2] = v.z; m[c][3] = v.w;        \
  }
  DEMUX(0, vp.x, vt.x)
  DEMUX(1, vp.y, vt.y)
  DEMUX(2, vp.z, vt.z)
  DEMUX(3, vp.w, vt.w)
#undef DEMUX

  int k = 1;
  while (k < WW) {
#pragma unroll
    for (int u = 0; u < 4; ++u) {
      const int kk0 = k + u;               // k is loop-carried; kk0-k static
      const float c2 = (float)(kk0 * kk0);
#pragma unroll
      for (int c = 0; c < 4; ++c) {
        const int y = y0 + c;
        const int lo = y - kk0;
        if (lo >= 0) {
          float4 v = s[wv][lo];
          m[c][0] = fminf(m[c][0], v.x + c2); m[c][1] = fminf(m[c][1], v.y + c2);
          m[c][2] = fminf(m[c][2], v.z + c2); m[c][3] = fminf(m[c][3], v.w + c2);
        }
        const int hi = y + kk0;
        if (hi < WW) {
          float4 v = s[wv][hi];
          m[c][0] = fminf(m[c][0], v.x + c2); m[c][1] = fminf(m[c][1], v.y + c2);
          m[c][2] = fminf(m[c][2], v.z + c2); m[c][3] = fminf(m[c][3], v.w + c2);
        }
      }
    }
    k += 4;
    float mx = 0.f;
#pragma unroll
    for (int c = 0; c < 4; ++c)
      mx = fmaxf(mx, fmaxf(fmaxf(m[c][0], m[c][1]), fmaxf(m[c][2], m[c][3])));
    const float nk2 = (float)(k * k);       // next group's first k
    if (__all(nk2 >= mx)) break;            // exact: no lane can improve
  }

  float val = 0.f;
#pragma unroll
  for (int c = 0; c < 4; ++c) {
    float pd = sqrtf(m[c][0]) + sqrtf(m[c][1]);   // pred_dist
    float td = sqrtf(m[c][2]) + sqrtf(m[c][3]);   // target_dist
    float diff = pd - td;
    val += diff * diff * td * td;                 // (pd-td)^2 * td^2
  }

  for (int off = 32; off > 0; off >>= 1) val += __shfl_down(val, off);
  if (lane == 0) partial[row] = val;
}

// ---------------------------------------------------------------------------
// Kernel C: reduce 8192 row partials in double, write mean.
// ---------------------------------------------------------------------------
__global__ __launch_bounds__(256) void finalize_kernel(
    const float* __restrict__ partial, float* __restrict__ out) {
  __shared__ double sd[256];
  double sum = 0.0;
  for (int i = threadIdx.x; i < BB * HH; i += 256) sum += (double)partial[i];
  sd[threadIdx.x] = sum;
  __syncthreads();
  for (int stride = 128; stride > 0; stride >>= 1) {
    if (threadIdx.x < stride) sd[threadIdx.x] += sd[threadIdx.x + stride];
    __syncthreads();
  }
  if (threadIdx.x == 0)
    out[0] = (float)(sd[0] / (double)((size_t)BB * HH * WW));
}

extern "C" void kernel_launch(void* const* d_in, const int* in_sizes, int n_in,
                              void* d_out, int out_size, void* d_ws, size_t ws_size,
                              hipStream_t stream) {
  const float* pred = (const float*)d_in[0];
  const float* tgt  = (const float*)d_in[1];
  float* out = (float*)d_out;

  // ws: P (256 KB), T (256 KB), DP2 (8 MB), DT2 (8 MB), partial (32 KB)
  unsigned int* P = (unsigned int*)d_ws;
  unsigned int* T = P + (size_t)BB * NW * WW;
  float* DP2 = (float*)(T + (size_t)BB * NW * WW);
  float* DT2 = DP2 + (size_t)BB * HH * WW;
  float* partial = DT2 + (size_t)BB * HH * WW;

  hipLaunchKernelGGL(bitmask_kernel, dim3(BB * NW * 4), dim3(256), 0, stream,
                     pred, tgt, P, T);
  hipLaunchKernelGGL(coledt_kernel, dim3(BB * 16), dim3(256), 0, stream,
                     P, T, DP2, DT2);
  hipLaunchKernelGGL(minplus_kernel, dim3(BB * HH / 4), dim3(256), 0, stream,
                     DP2, DT2, partial);
  hipLaunchKernelGGL(finalize_kernel, dim3(1), dim3(256), 0, stream,
                     partial, out);
}

// Round 8
// 28.816 us; speedup vs baseline: 1.4775x; 1.4775x over previous
//
#include <hip/hip_runtime.h>
#include <math.h>

#define HH 256
#define WW 256
#define BB 32
#define NW 8  // 256 rows = 8 x u32 words per column bitmask

// ---------------------------------------------------------------------------
// Kernel A: build column bitmasks.  P bit = (pred > 0.5), T bit = (target==1).
// Grid: BB*NW*4 = 1024 blocks; block = (b, word-row j, column-quarter wq).
// ---------------------------------------------------------------------------
__global__ __launch_bounds__(256) void bitmask_kernel(
    const float* __restrict__ pred, const float* __restrict__ tgt,
    unsigned int* __restrict__ P, unsigned int* __restrict__ T) {
  const int b  = blockIdx.x >> 5;
  const int j  = (blockIdx.x >> 2) & 7;
  const int wq = blockIdx.x & 3;
  const int r    = threadIdx.x >> 6;   // wave id: row-subset (8 rows)
  const int lane = threadIdx.x & 63;
  const int col  = wq * 64 + lane;
  const int row0 = j * 32 + r * 8;

  const float* pin = pred + (size_t)b * (HH * WW) + row0 * WW + col;
  const float* tin = tgt  + (size_t)b * (HH * WW) + row0 * WW + col;
  unsigned int pb = 0, tb = 0;
#pragma unroll
  for (int i = 0; i < 8; ++i) {
    pb |= (pin[i * WW] > 0.5f ? 1u : 0u) << i;
    tb |= (tin[i * WW] == 1.0f ? 1u : 0u) << i;
  }

  __shared__ unsigned int sP[4][64], sT[4][64];
  sP[r][lane] = pb << (r * 8);
  sT[r][lane] = tb << (r * 8);
  __syncthreads();
  if (r == 0) {
    P[((size_t)b * NW + j) * WW + col] =
        sP[0][lane] | sP[1][lane] | sP[2][lane] | sP[3][lane];
    T[((size_t)b * NW + j) * WW + col] =
        sT[0][lane] | sT[1][lane] | sT[2][lane] | sT[3][lane];
  }
}

// ---------------------------------------------------------------------------
// Kernel B (FUSED coledt+minplus): block = (b, stripe j of 32 rows),
// 512 threads.
//   Phase 1: threads 0-255 (pred) / 256-511 (target) compute the per-column
//     1D distance chains for the stripe's 32 rows via edge masks and write
//     SIGN-ENCODED g^2 (own? -g^2 : +g^2) straight into LDS.  No global
//     intermediate — the 32 MB DP2/DT2 round-trip is gone.
//   Phase 2: 8 waves x 4 rows each run the exact early-exit min-plus from
//     LDS (lane owns cols lane+64c -> stride-1-dword, conflict-free),
//     fused loss, wave reduce, one partial per (block, wave).
// ---------------------------------------------------------------------------
__global__ __launch_bounds__(512) void stripe_kernel(
    const unsigned int* __restrict__ P, const unsigned int* __restrict__ T,
    float* __restrict__ partial) {
  const int blk = blockIdx.x;          // b*8 + j
  const int b = blk >> 3;
  const int j = blk & 7;
  const int tid = threadIdx.x;

  __shared__ float sp[32][WW];  // sign-encoded pred g^2 for the stripe
  __shared__ float st[32][WW];  // sign-encoded target g^2

  // ---- phase 1: column chains (one map per thread-half) ----
  {
    const int mp = tid >> 8;           // 0: pred, 1: target
    const int w  = tid & 255;
    const unsigned int* M = mp ? T : P;

    unsigned int Wd[NW];
#pragma unroll
    for (int jj = 0; jj < NW; ++jj)
      Wd[jj] = M[((size_t)b * NW + jj) * WW + w];

    unsigned int E[NW];
#pragma unroll
    for (int jj = 0; jj < NW - 1; ++jj)
      E[jj] = Wd[jj] ^ ((Wd[jj] >> 1) | (Wd[jj + 1] << 31));
    E[NW - 1] = (Wd[NW - 1] ^ (Wd[NW - 1] >> 1)) & 0x7FFFFFFFu;

    unsigned int EJ = 0, EJm1 = 0, WJ = 0;
#pragma unroll
    for (int jj = 0; jj < NW; ++jj) {
      if (j == jj) { EJ = E[jj]; WJ = Wd[jj]; }
      if (j - 1 == jj) EJm1 = E[jj];
    }

    int emax = -100000;
#pragma unroll
    for (int jj = 0; jj < NW - 1; ++jj)
      if (jj < j && E[jj]) emax = 32 * jj + 31 - __builtin_clz(E[jj]);
    int D = (j * 32 - 1) - emax;
    if (D > 513) D = 513;

    int emin = 100000;
#pragma unroll
    for (int jj = NW - 1; jj >= 1; --jj)
      if (jj > j && E[jj]) emin = 32 * jj + __builtin_ctz(E[jj]);
    int U = (emin + 1) - (j * 32 + 32);
    if (U > 513) U = 513;

    const unsigned int EQ = (EJ << 1) | (j ? (EJm1 >> 31) : 0u);

    unsigned int dn[16];
#pragma unroll
    for (int i = 0; i < 32; ++i) {
      D = ((EQ >> i) & 1u) ? 1 : (D + 1);
      if (i & 1) dn[i >> 1] |= (unsigned int)D << 16;
      else       dn[i >> 1] = (unsigned int)D;
    }

#pragma unroll
    for (int i = 31; i >= 0; --i) {
      U = ((EJ >> i) & 1u) ? 1 : (U + 1);
      int dnv = (int)((dn[i >> 1] >> ((i & 1) * 16)) & 0xFFFFu);
      int g = min(min(dnv, U), 512);   // cap = H+W (exact, incl. empty cols)
      float g2 = (float)(g * g);
      float v = ((WJ >> i) & 1u) ? -g2 : g2;
      if (mp == 0) sp[i][w] = v;
      else         st[i][w] = v;
    }
  }
  __syncthreads();

  // ---- phase 2: min-plus, 4 rows per wave, no further barriers ----
  const int wv = tid >> 6;
  const int lane = tid & 63;
  float acc = 0.f;

  for (int rr = 0; rr < 4; ++rr) {
    const int r = wv * 4 + rr;
    float m[4][4];                     // [col-group][map], static idx only
#pragma unroll
    for (int c = 0; c < 4; ++c) {
      float vp = sp[r][lane + 64 * c];
      float vt = st[r][lane + 64 * c];
      m[c][0] = fmaxf(vp, 0.f); m[c][1] = fmaxf(-vp, 0.f);
      m[c][2] = fmaxf(vt, 0.f); m[c][3] = fmaxf(-vt, 0.f);
    }

    for (int k = 1; k < WW; ++k) {
      const float c2 = (float)(k * k);
      float mx = 0.f;
#pragma unroll
      for (int c = 0; c < 4; ++c)
        mx = fmaxf(mx, fmaxf(fmaxf(m[c][0], m[c][1]), fmaxf(m[c][2], m[c][3])));
      if (c2 >= mx) break;             // exact: remaining candidates >= k^2
#pragma unroll
      for (int c = 0; c < 4; ++c) {
        const int y = lane + 64 * c;
        const int lo = y - k;
        if (lo >= 0) {
          float vp = sp[r][lo], vt = st[r][lo];
          m[c][0] = fminf(m[c][0], fmaxf(vp, 0.f) + c2);
          m[c][1] = fminf(m[c][1], fmaxf(-vp, 0.f) + c2);
          m[c][2] = fminf(m[c][2], fmaxf(vt, 0.f) + c2);
          m[c][3] = fminf(m[c][3], fmaxf(-vt, 0.f) + c2);
        }
        const int hi = y + k;
        if (hi < WW) {
          float vp = sp[r][hi], vt = st[r][hi];
          m[c][0] = fminf(m[c][0], fmaxf(vp, 0.f) + c2);
          m[c][1] = fminf(m[c][1], fmaxf(-vp, 0.f) + c2);
          m[c][2] = fminf(m[c][2], fmaxf(vt, 0.f) + c2);
          m[c][3] = fminf(m[c][3], fmaxf(-vt, 0.f) + c2);
        }
      }
    }

    float val = 0.f;
#pragma unroll
    for (int c = 0; c < 4; ++c) {
      float pd = sqrtf(m[c][0]) + sqrtf(m[c][1]);   // pred_dist
      float td = sqrtf(m[c][2]) + sqrtf(m[c][3]);   // target_dist
      float diff = pd - td;
      val += diff * diff * td * td;                 // (pd-td)^2 * td^2
    }
    for (int off = 32; off > 0; off >>= 1) val += __shfl_down(val, off);
    acc += val;                        // only lane 0's acc is consumed
  }

  if (lane == 0) partial[blk * 8 + wv] = acc;
}

// ---------------------------------------------------------------------------
// Kernel C: reduce 2048 partials in double, write mean.
// ---------------------------------------------------------------------------
__global__ __launch_bounds__(256) void finalize_kernel(
    const float* __restrict__ partial, float* __restrict__ out) {
  __shared__ double sd[256];
  double sum = 0.0;
  for (int i = threadIdx.x; i < 2048; i += 256) sum += (double)partial[i];
  sd[threadIdx.x] = sum;
  __syncthreads();
  for (int stride = 128; stride > 0; stride >>= 1) {
    if (threadIdx.x < stride) sd[threadIdx.x] += sd[threadIdx.x + stride];
    __syncthreads();
  }
  if (threadIdx.x == 0)
    out[0] = (float)(sd[0] / (double)((size_t)BB * HH * WW));
}

extern "C" void kernel_launch(void* const* d_in, const int* in_sizes, int n_in,
                              void* d_out, int out_size, void* d_ws, size_t ws_size,
                              hipStream_t stream) {
  const float* pred = (const float*)d_in[0];
  const float* tgt  = (const float*)d_in[1];
  float* out = (float*)d_out;

  // ws: P (256 KB), T (256 KB), partial (8 KB)
  unsigned int* P = (unsigned int*)d_ws;
  unsigned int* T = P + (size_t)BB * NW * WW;
  float* partial = (float*)(T + (size_t)BB * NW * WW);

  hipLaunchKernelGGL(bitmask_kernel, dim3(BB * NW * 4), dim3(256), 0, stream,
                     pred, tgt, P, T);
  hipLaunchKernelGGL(stripe_kernel, dim3(BB * NW), dim3(512), 0, stream,
                     P, T, partial);
  hipLaunchKernelGGL(finalize_kernel, dim3(1), dim3(256), 0, stream,
                     partial, out);
}